// Round 15
// baseline (900.462 us; speedup 1.0000x reference)
//
#include <hip/hip_runtime.h>
#include <hip/hip_bf16.h>

#define NB 4096
#define NS 32
#define NI 16
#define NH 32

typedef float f32x2 __attribute__((ext_vector_type(2)));

// Wave-local LDS write->read turnaround: drain lgkm, fence the compiler.
__device__ __forceinline__ void fence() {
    __builtin_amdgcn_wave_barrier();
    asm volatile("s_waitcnt lgkmcnt(0)" ::: "memory");
    __builtin_amdgcn_wave_barrier();
}

// Cross-half sum via the compiler-known permlane builtin (hazard-safe, VALU).
__device__ __forceinline__ float xhsum(float x) {
    auto p = __builtin_amdgcn_permlane32_swap(
        (int)__float_as_uint(x), (int)__float_as_uint(x), false, false);
    return __uint_as_float((unsigned)p[0]) + __uint_as_float((unsigned)p[1]);
}

__device__ __forceinline__ f32x2 pkfma(f32x2 a, f32x2 b, f32x2 c) {
    return __builtin_elementwise_fma(a, b, c);   // v_pk_fma_f32
}

// R14 lesson: grid (4096 elems / elems-per-wave) caps TLP, not block size.
// R11-form (ILP-2) is the most VALU-efficient measured (146 instr/elem vs
// R9's 287); its limiter is latency at 2 waves/SIMD. R15: ILP-4 — 4 elems
// per wave (1024 waves, 1/SIMD): fences, LDS addressing, and GRU weight
// reads amortize 4-way; 4 independent chains hide LDS latency in-wave.
// waves_per_eu(1,1): budget 512 regs, zero spill pressure (live ~180).
__global__ void __launch_bounds__(128)
__attribute__((amdgpu_waves_per_eu(1, 1)))
odernn_kernel(
    const float* __restrict__ x,    // (B,S,I)
    const float* __restrict__ t,    // (B,S)
    const float* __restrict__ gWih, // (96,16)
    const float* __restrict__ gWhh, // (96,32)
    const float* __restrict__ gbih, // (96)
    const float* __restrict__ gbhh, // (96)
    const float* __restrict__ oW1,  // (64,32)
    const float* __restrict__ ob1,  // (64)
    const float* __restrict__ oW2,  // (32,64)
    const float* __restrict__ ob2,  // (32)
    const float* __restrict__ oW3,  // (32,32)
    const float* __restrict__ ob3,  // (32)
    const float* __restrict__ fW1,  // (64,32)
    const float* __restrict__ fb1,  // (64)
    const float* __restrict__ fW2,  // (1,64)
    const float* __restrict__ fb2,  // (1)
    float* __restrict__ outp)       // (B,1)
{
    const int tid  = threadIdx.x;
    const int lane = tid & 63;
    const int wid  = tid >> 6;               // 0..1
    const int bb   = blockIdx.x * 8 + wid * 4;   // 4 elements per wave
    const int r    = lane & 31;
    const int hf   = lane >> 5;

    // ---- LDS: GRU weights (col-major [col][32 rows]) + per-elem buffers ----
    __shared__ float sWr[48 * 32];
    __shared__ float sWz[48 * 32];
    __shared__ float sWnh[32 * 32];
    __shared__ float sWni[16 * 32];
    __shared__ __align__(16) float buf[2][4][64];

    for (int i = tid; i < 48 * 32; i += 128) {
        int c = i >> 5, r0 = i & 31;
        sWr[i] = (c < 16) ? gWih[r0 * 16 + c]        : gWhh[r0 * 32 + (c - 16)];
        sWz[i] = (c < 16) ? gWih[(32 + r0) * 16 + c] : gWhh[(32 + r0) * 32 + (c - 16)];
    }
    for (int i = tid; i < 32 * 32; i += 128) {
        int c = i >> 5, r0 = i & 31;
        sWnh[i] = gWhh[(64 + r0) * 32 + c];
    }
    for (int i = tid; i < 16 * 32; i += 128) {
        int c = i >> 5, r0 = i & 31;
        sWni[i] = gWih[(64 + r0) * 16 + c];
    }
    __syncthreads();

    float* bw0 = buf[wid][0];
    float* bw1 = buf[wid][1];
    float* bw2 = buf[wid][2];
    float* bw3 = buf[wid][3];
    const float4* bb0 = reinterpret_cast<const float4*>(bw0);
    const float4* bb1 = reinterpret_cast<const float4*>(bw1);
    const float4* bb2 = reinterpret_cast<const float4*>(bw2);
    const float4* bb3 = reinterpret_cast<const float4*>(bw3);

    // ------- ODE MLP weights -> NAMED per-lane f32x2 registers (R11) -------
    f32x2 w1_0, w1_1, w1_2, w1_3, w1_4, w1_5, w1_6, w1_7,
          w1_8, w1_9, w1_10, w1_11, w1_12, w1_13, w1_14, w1_15;
    f32x2 w2_0, w2_1, w2_2, w2_3, w2_4, w2_5, w2_6, w2_7,
          w2_8, w2_9, w2_10, w2_11, w2_12, w2_13, w2_14, w2_15;
    f32x2 w3_0, w3_1, w3_2, w3_3, w3_4, w3_5, w3_6, w3_7;
    {
        const float4* p1 = reinterpret_cast<const float4*>(oW1) + lane * 8;
        float4 v;
#define LD2(i, dA, dB) { v = p1[i]; dA = f32x2{v.x, v.y}; dB = f32x2{v.z, v.w}; }
        LD2(0, w1_0,  w1_1)  LD2(1, w1_2,  w1_3)
        LD2(2, w1_4,  w1_5)  LD2(3, w1_6,  w1_7)
        LD2(4, w1_8,  w1_9)  LD2(5, w1_10, w1_11)
        LD2(6, w1_12, w1_13) LD2(7, w1_14, w1_15)
#undef LD2
        const float4* p2 = reinterpret_cast<const float4*>(oW2) + r * 16 + hf * 8;
#define LD2(i, dA, dB) { v = p2[i]; dA = f32x2{v.x, v.y}; dB = f32x2{v.z, v.w}; }
        LD2(0, w2_0,  w2_1)  LD2(1, w2_2,  w2_3)
        LD2(2, w2_4,  w2_5)  LD2(3, w2_6,  w2_7)
        LD2(4, w2_8,  w2_9)  LD2(5, w2_10, w2_11)
        LD2(6, w2_12, w2_13) LD2(7, w2_14, w2_15)
#undef LD2
        const float4* p3 = reinterpret_cast<const float4*>(oW3) + r * 8 + hf * 4;
#define LD2(i, dA, dB) { v = p3[i]; dA = f32x2{v.x, v.y}; dB = f32x2{v.z, v.w}; }
        LD2(0, w3_0, w3_1)  LD2(1, w3_2, w3_3)
        LD2(2, w3_4, w3_5)  LD2(3, w3_6, w3_7)
#undef LD2
    }
    const float b1r = ob1[lane];
    const float b2r = ob2[r];
    const float b3r = ob3[r];

    const float brr = gbih[r]      + gbhh[r];
    const float bzz = gbih[32 + r] + gbhh[32 + r];
    const float bin = gbih[64 + r];
    const float bhn = gbhh[64 + r];

    const float* wrp  = &sWr[(hf * 24) * 32 + r];
    const float* wzp  = &sWz[(hf * 24) * 32 + r];
    const float* wnhp = &sWnh[(hf * 16) * 32 + r];
    const float* wnip = &sWni[r];

    // --- ODE MLP for 4 elements; per-element math identical to R11 ---
    auto ode_f4 = [&](float y0, float y1, float y2, float y3,
                      float& o0, float& o1, float& o2, float& o3) {
        bw0[hf * 32 + r] = y0;
        bw1[hf * 32 + r] = y1;
        bw2[hf * 32 + r] = y2;
        bw3[hf * 32 + r] = y3;
        fence();
        f32x2 A0 = f32x2{b1r, 0.f}, A1 = f32x2{b1r, 0.f},
              A2 = f32x2{b1r, 0.f}, A3 = f32x2{b1r, 0.f};
#define S1M(kk, wA, wB) { \
        float4 c0 = bb0[kk], c1 = bb1[kk], c2 = bb2[kk], c3 = bb3[kk]; \
        A0 = pkfma(wA, f32x2{c0.x, c0.y}, A0); A0 = pkfma(wB, f32x2{c0.z, c0.w}, A0); \
        A1 = pkfma(wA, f32x2{c1.x, c1.y}, A1); A1 = pkfma(wB, f32x2{c1.z, c1.w}, A1); \
        A2 = pkfma(wA, f32x2{c2.x, c2.y}, A2); A2 = pkfma(wB, f32x2{c2.z, c2.w}, A2); \
        A3 = pkfma(wA, f32x2{c3.x, c3.y}, A3); A3 = pkfma(wB, f32x2{c3.z, c3.w}, A3); }
        S1M(0, w1_0,  w1_1)  S1M(1, w1_2,  w1_3)
        S1M(2, w1_4,  w1_5)  S1M(3, w1_6,  w1_7)
        S1M(4, w1_8,  w1_9)  S1M(5, w1_10, w1_11)
        S1M(6, w1_12, w1_13) S1M(7, w1_14, w1_15)
#undef S1M
        float h0 = fmaxf(A0.x + A0.y, 0.f);
        float h1 = fmaxf(A1.x + A1.y, 0.f);
        float h2 = fmaxf(A2.x + A2.y, 0.f);
        float h3 = fmaxf(A3.x + A3.y, 0.f);
        bw0[lane] = h0;
        bw1[lane] = h1;
        bw2[lane] = h2;
        bw3[lane] = h3;
        fence();
        f32x2 B0 = f32x2{0.f, 0.f}, B1 = f32x2{0.f, 0.f},
              B2 = f32x2{0.f, 0.f}, B3 = f32x2{0.f, 0.f};
        const int o2i = hf * 8;
#define S2M(kk, wA, wB) { \
        float4 c0 = bb0[o2i + kk], c1 = bb1[o2i + kk], c2 = bb2[o2i + kk], c3 = bb3[o2i + kk]; \
        B0 = pkfma(wA, f32x2{c0.x, c0.y}, B0); B0 = pkfma(wB, f32x2{c0.z, c0.w}, B0); \
        B1 = pkfma(wA, f32x2{c1.x, c1.y}, B1); B1 = pkfma(wB, f32x2{c1.z, c1.w}, B1); \
        B2 = pkfma(wA, f32x2{c2.x, c2.y}, B2); B2 = pkfma(wB, f32x2{c2.z, c2.w}, B2); \
        B3 = pkfma(wA, f32x2{c3.x, c3.y}, B3); B3 = pkfma(wB, f32x2{c3.z, c3.w}, B3); }
        S2M(0, w2_0,  w2_1)  S2M(1, w2_2,  w2_3)
        S2M(2, w2_4,  w2_5)  S2M(3, w2_6,  w2_7)
        S2M(4, w2_8,  w2_9)  S2M(5, w2_10, w2_11)
        S2M(6, w2_12, w2_13) S2M(7, w2_14, w2_15)
#undef S2M
        float a20 = fmaxf(xhsum(B0.x + B0.y) + b2r, 0.f);
        float a21 = fmaxf(xhsum(B1.x + B1.y) + b2r, 0.f);
        float a22 = fmaxf(xhsum(B2.x + B2.y) + b2r, 0.f);
        float a23 = fmaxf(xhsum(B3.x + B3.y) + b2r, 0.f);
        bw0[hf * 32 + r] = a20;
        bw1[hf * 32 + r] = a21;
        bw2[hf * 32 + r] = a22;
        bw3[hf * 32 + r] = a23;
        fence();
        f32x2 C0 = f32x2{0.f, 0.f}, C1 = f32x2{0.f, 0.f},
              C2 = f32x2{0.f, 0.f}, C3 = f32x2{0.f, 0.f};
        const int o3i = hf * 4;
#define S3M(kk, wA, wB) { \
        float4 c0 = bb0[o3i + kk], c1 = bb1[o3i + kk], c2 = bb2[o3i + kk], c3 = bb3[o3i + kk]; \
        C0 = pkfma(wA, f32x2{c0.x, c0.y}, C0); C0 = pkfma(wB, f32x2{c0.z, c0.w}, C0); \
        C1 = pkfma(wA, f32x2{c1.x, c1.y}, C1); C1 = pkfma(wB, f32x2{c1.z, c1.w}, C1); \
        C2 = pkfma(wA, f32x2{c2.x, c2.y}, C2); C2 = pkfma(wB, f32x2{c2.z, c2.w}, C2); \
        C3 = pkfma(wA, f32x2{c3.x, c3.y}, C3); C3 = pkfma(wB, f32x2{c3.z, c3.w}, C3); }
        S3M(0, w3_0, w3_1)  S3M(1, w3_2, w3_3)
        S3M(2, w3_4, w3_5)  S3M(3, w3_6, w3_7)
#undef S3M
        o0 = xhsum(C0.x + C0.y) + b3r;
        o1 = xhsum(C1.x + C1.y) + b3r;
        o2 = xhsum(C2.x + C2.y) + b3r;
        o3 = xhsum(C3.x + C3.y) + b3r;
    };

    // ---------- time loop ----------
    float hv0 = 0.f, hv1 = 0.f, hv2 = 0.f, hv3 = 0.f;
    float outv0 = 0.f, outv1 = 0.f, outv2 = 0.f, outv3 = 0.f;

    #pragma unroll 1
    for (int s = 0; s < NS - 1; ++s) {
        const float* xr0 = x + ((size_t)(bb + 0) * NS + s) * NI;
        const float* xr1 = x + ((size_t)(bb + 1) * NS + s) * NI;
        const float* xr2 = x + ((size_t)(bb + 2) * NS + s) * NI;
        const float* xr3 = x + ((size_t)(bb + 3) * NS + s) * NI;
        if (hf == 0) {
            bw0[16 + r] = hv0;
            bw1[16 + r] = hv1;
            bw2[16 + r] = hv2;
            bw3[16 + r] = hv3;
        } else {
            bw0[r & 15] = xr0[r & 15];
            bw1[r & 15] = xr1[r & 15];
            bw2[r & 15] = xr2[r & 15];
            bw3[r & 15] = xr3[r & 15];
        }
        fence();

        float ar0 = 0.f, ar1 = 0.f, ar2 = 0.f, ar3 = 0.f;
        float az0 = 0.f, az1 = 0.f, az2 = 0.f, az3 = 0.f;
        #pragma unroll
        for (int kk = 0; kk < 6; ++kk) {
            float4 c0 = bb0[hf * 6 + kk];
            float4 c1 = bb1[hf * 6 + kk];
            float4 c2 = bb2[hf * 6 + kk];
            float4 c3 = bb3[hf * 6 + kk];
            float w;
#define G4(acc, comp, wv) w = wv; \
            acc##0 = fmaf(w, c0.comp, acc##0); acc##1 = fmaf(w, c1.comp, acc##1); \
            acc##2 = fmaf(w, c2.comp, acc##2); acc##3 = fmaf(w, c3.comp, acc##3);
            G4(ar, x, wrp[(4*kk  )*32])  G4(ar, y, wrp[(4*kk+1)*32])
            G4(ar, z, wrp[(4*kk+2)*32])  G4(ar, w, wrp[(4*kk+3)*32])
            G4(az, x, wzp[(4*kk  )*32])  G4(az, y, wzp[(4*kk+1)*32])
            G4(az, z, wzp[(4*kk+2)*32])  G4(az, w, wzp[(4*kk+3)*32])
#undef G4
        }
        float in0 = 0.f, in1 = 0.f, in2 = 0.f, in3 = 0.f;
        float hn0 = 0.f, hn1 = 0.f, hn2 = 0.f, hn3 = 0.f;
        #pragma unroll
        for (int kk = 0; kk < 4; ++kk) {
            float4 c0 = bb0[kk];
            float4 c1 = bb1[kk];
            float4 c2 = bb2[kk];
            float4 c3 = bb3[kk];
            float w;
#define G4(acc, comp, wv) w = wv; \
            acc##0 = fmaf(w, c0.comp, acc##0); acc##1 = fmaf(w, c1.comp, acc##1); \
            acc##2 = fmaf(w, c2.comp, acc##2); acc##3 = fmaf(w, c3.comp, acc##3);
            G4(in, x, wnip[(4*kk  )*32])  G4(in, y, wnip[(4*kk+1)*32])
            G4(in, z, wnip[(4*kk+2)*32])  G4(in, w, wnip[(4*kk+3)*32])
#undef G4
        }
        #pragma unroll
        for (int kk = 0; kk < 4; ++kk) {
            float4 c0 = bb0[4 + hf * 4 + kk];
            float4 c1 = bb1[4 + hf * 4 + kk];
            float4 c2 = bb2[4 + hf * 4 + kk];
            float4 c3 = bb3[4 + hf * 4 + kk];
            float w;
#define G4(acc, comp, wv) w = wv; \
            acc##0 = fmaf(w, c0.comp, acc##0); acc##1 = fmaf(w, c1.comp, acc##1); \
            acc##2 = fmaf(w, c2.comp, acc##2); acc##3 = fmaf(w, c3.comp, acc##3);
            G4(hn, x, wnhp[(4*kk  )*32])  G4(hn, y, wnhp[(4*kk+1)*32])
            G4(hn, z, wnhp[(4*kk+2)*32])  G4(hn, w, wnhp[(4*kk+3)*32])
#undef G4
        }
        ar0 = xhsum(ar0) + brr; ar1 = xhsum(ar1) + brr;
        ar2 = xhsum(ar2) + brr; ar3 = xhsum(ar3) + brr;
        az0 = xhsum(az0) + bzz; az1 = xhsum(az1) + bzz;
        az2 = xhsum(az2) + bzz; az3 = xhsum(az3) + bzz;
        hn0 = xhsum(hn0) + bhn; hn1 = xhsum(hn1) + bhn;
        hn2 = xhsum(hn2) + bhn; hn3 = xhsum(hn3) + bhn;
        in0 += bin; in1 += bin; in2 += bin; in3 += bin;

#define GATE(i) { \
        float rg = 1.0f / (1.0f + __expf(-ar##i)); \
        float zg = 1.0f / (1.0f + __expf(-az##i)); \
        float ng = tanhf(fmaf(rg, hn##i, in##i)); \
        outv##i = (1.0f - zg) * ng + zg * hv##i; }
        GATE(0) GATE(1) GATE(2) GATE(3)
#undef GATE

        hv0 = outv0; hv1 = outv1; hv2 = outv2; hv3 = outv3;
        if (s < NS - 2) {
            const float ddt0 = (t[(size_t)(bb+0) * NS + s + 1] - t[(size_t)(bb+0) * NS + s]) * 0.25f;
            const float ddt1 = (t[(size_t)(bb+1) * NS + s + 1] - t[(size_t)(bb+1) * NS + s]) * 0.25f;
            const float ddt2 = (t[(size_t)(bb+2) * NS + s + 1] - t[(size_t)(bb+2) * NS + s]) * 0.25f;
            const float ddt3 = (t[(size_t)(bb+3) * NS + s + 1] - t[(size_t)(bb+3) * NS + s]) * 0.25f;
            float hi0 = outv0, hi1 = outv1, hi2 = outv2, hi3 = outv3;
            #pragma unroll 1
            for (int sub = 0; sub < 4; ++sub) {
                float k1_0, k1_1, k1_2, k1_3, k2_0, k2_1, k2_2, k2_3,
                      k3_0, k3_1, k3_2, k3_3, k4_0, k4_1, k4_2, k4_3,
                      k5_0, k5_1, k5_2, k5_3, k6_0, k6_1, k6_2, k6_3;
                ode_f4(hi0, hi1, hi2, hi3, k1_0, k1_1, k1_2, k1_3);
#define Y2(i) fmaf(ddt##i, 0.2f * k1_##i, hi##i)
                ode_f4(Y2(0), Y2(1), Y2(2), Y2(3), k2_0, k2_1, k2_2, k2_3);
#undef Y2
#define Y3(i) fmaf(ddt##i, fmaf((float)(9.0/40.0), k2_##i, (float)(3.0/40.0) * k1_##i), hi##i)
                ode_f4(Y3(0), Y3(1), Y3(2), Y3(3), k3_0, k3_1, k3_2, k3_3);
#undef Y3
#define Y4(i) fmaf(ddt##i, fmaf((float)(32.0/9.0), k3_##i, \
                  fmaf(-(float)(56.0/15.0), k2_##i, (float)(44.0/45.0) * k1_##i)), hi##i)
                ode_f4(Y4(0), Y4(1), Y4(2), Y4(3), k4_0, k4_1, k4_2, k4_3);
#undef Y4
#define Y5(i) fmaf(ddt##i, fmaf(-(float)(212.0/729.0), k4_##i, \
                  fmaf((float)(64448.0/6561.0), k3_##i, \
                  fmaf(-(float)(25360.0/2187.0), k2_##i, (float)(19372.0/6561.0) * k1_##i))), hi##i)
                ode_f4(Y5(0), Y5(1), Y5(2), Y5(3), k5_0, k5_1, k5_2, k5_3);
#undef Y5
#define Y6(i) fmaf(ddt##i, fmaf(-(float)(5103.0/18656.0), k5_##i, \
                  fmaf((float)(49.0/176.0), k4_##i, \
                  fmaf((float)(46732.0/5247.0), k3_##i, \
                  fmaf(-(float)(355.0/33.0), k2_##i, (float)(9017.0/3168.0) * k1_##i)))), hi##i)
                ode_f4(Y6(0), Y6(1), Y6(2), Y6(3), k6_0, k6_1, k6_2, k6_3);
#undef Y6
#define YF(i) hi##i = fmaf(ddt##i, fmaf((float)(11.0/84.0), k6_##i, \
                  fmaf(-(float)(2187.0/6784.0), k5_##i, \
                  fmaf((float)(125.0/192.0), k4_##i, \
                  fmaf((float)(500.0/1113.0), k3_##i, (float)(35.0/384.0) * k1_##i)))), hi##i);
                YF(0) YF(1) YF(2) YF(3)
#undef YF
            }
            hv0 = hi0; hv1 = hi1; hv2 = hi2; hv3 = hi3;
        }
    }

    // ---------- FC head: relu(out @ fW1.T + fb1) @ fW2.T + fb2 ----------
    bw0[hf * 32 + r] = outv0;
    bw1[hf * 32 + r] = outv1;
    bw2[hf * 32 + r] = outv2;
    bw3[hf * 32 + r] = outv3;
    fence();
    f32x2 ac0 = f32x2{fb1[lane], 0.0f};
    f32x2 ac1 = f32x2{fb1[lane], 0.0f};
    f32x2 ac2 = f32x2{fb1[lane], 0.0f};
    f32x2 ac3 = f32x2{fb1[lane], 0.0f};
    {
        const float4* fw = reinterpret_cast<const float4*>(fW1) + lane * 8;
        #pragma unroll
        for (int kk = 0; kk < 8; ++kk) {
            float4 wv = fw[kk];
            float4 c0 = bb0[kk];
            float4 c1 = bb1[kk];
            float4 c2 = bb2[kk];
            float4 c3 = bb3[kk];
            ac0 = pkfma(f32x2{wv.x, wv.y}, f32x2{c0.x, c0.y}, ac0);
            ac0 = pkfma(f32x2{wv.z, wv.w}, f32x2{c0.z, c0.w}, ac0);
            ac1 = pkfma(f32x2{wv.x, wv.y}, f32x2{c1.x, c1.y}, ac1);
            ac1 = pkfma(f32x2{wv.z, wv.w}, f32x2{c1.z, c1.w}, ac1);
            ac2 = pkfma(f32x2{wv.x, wv.y}, f32x2{c2.x, c2.y}, ac2);
            ac2 = pkfma(f32x2{wv.z, wv.w}, f32x2{c2.z, c2.w}, ac2);
            ac3 = pkfma(f32x2{wv.x, wv.y}, f32x2{c3.x, c3.y}, ac3);
            ac3 = pkfma(f32x2{wv.z, wv.w}, f32x2{c3.z, c3.w}, ac3);
        }
    }
    float fw2v = fW2[lane];
    float p0 = fmaxf(ac0.x + ac0.y, 0.0f) * fw2v;
    float p1 = fmaxf(ac1.x + ac1.y, 0.0f) * fw2v;
    float p2 = fmaxf(ac2.x + ac2.y, 0.0f) * fw2v;
    float p3 = fmaxf(ac3.x + ac3.y, 0.0f) * fw2v;
    #pragma unroll
    for (int m = 1; m < 64; m <<= 1) {
        p0 += __shfl_xor(p0, m, 64);
        p1 += __shfl_xor(p1, m, 64);
        p2 += __shfl_xor(p2, m, 64);
        p3 += __shfl_xor(p3, m, 64);
    }
    if (lane == 0) {
        float bias = fb2[0];
        outp[bb + 0] = p0 + bias;
        outp[bb + 1] = p1 + bias;
        outp[bb + 2] = p2 + bias;
        outp[bb + 3] = p3 + bias;
    }
}

extern "C" void kernel_launch(void* const* d_in, const int* in_sizes, int n_in,
                              void* d_out, int out_size, void* d_ws, size_t ws_size,
                              hipStream_t stream) {
    (void)in_sizes; (void)n_in; (void)d_ws; (void)ws_size; (void)out_size;
    odernn_kernel<<<dim3(NB / 8), dim3(128), 0, stream>>>(
        (const float*)d_in[0],  (const float*)d_in[1],
        (const float*)d_in[2],  (const float*)d_in[3],
        (const float*)d_in[4],  (const float*)d_in[5],
        (const float*)d_in[6],  (const float*)d_in[7],
        (const float*)d_in[8],  (const float*)d_in[9],
        (const float*)d_in[10], (const float*)d_in[11],
        (const float*)d_in[12], (const float*)d_in[13],
        (const float*)d_in[14], (const float*)d_in[15],
        (float*)d_out);
}

// Round 16
// 749.604 us; speedup vs baseline: 1.2013x; 1.2013x over previous
//
#include <hip/hip_runtime.h>
#include <hip/hip_bf16.h>

#define NB 4096
#define NS 32
#define NI 16
#define NH 32

typedef float f32x2 __attribute__((ext_vector_type(2)));

// Wave-local LDS write->read turnaround: drain lgkm, fence the compiler.
__device__ __forceinline__ void fence() {
    __builtin_amdgcn_wave_barrier();
    asm volatile("s_waitcnt lgkmcnt(0)" ::: "memory");
    __builtin_amdgcn_wave_barrier();
}

// Cross-half sum via the compiler-known permlane builtin (hazard-safe, VALU).
__device__ __forceinline__ float xhsum(float x) {
    auto p = __builtin_amdgcn_permlane32_swap(
        (int)__float_as_uint(x), (int)__float_as_uint(x), false, false);
    return __uint_as_float((unsigned)p[0]) + __uint_as_float((unsigned)p[1]);
}

__device__ __forceinline__ f32x2 pkfma(f32x2 a, f32x2 b, f32x2 c) {
    return __builtin_elementwise_fma(a, b, c);   // v_pk_fma_f32 on gfx950
}

// Ledger: VALU issue-cycles/elem is ~constant across R9/R11/R15 forms; the
// differentiator is resident waves. R9 (1 elem/wave) has 4096 waves = 4/SIMD
// available and VGPR=112 <= 128, but its waves_per_eu(2,2) MAX capped
// residency at 2/SIMD. R16 = R9 + (2,4): min=2 keeps the proven relaxed
// allocation (112 VGPR, zero scratch), max=4 doubles hardware residency.
__global__ void __launch_bounds__(256)
__attribute__((amdgpu_waves_per_eu(2, 4)))
odernn_kernel(
    const float* __restrict__ x,    // (B,S,I)
    const float* __restrict__ t,    // (B,S)
    const float* __restrict__ gWih, // (96,16)
    const float* __restrict__ gWhh, // (96,32)
    const float* __restrict__ gbih, // (96)
    const float* __restrict__ gbhh, // (96)
    const float* __restrict__ oW1,  // (64,32)
    const float* __restrict__ ob1,  // (64)
    const float* __restrict__ oW2,  // (32,64)
    const float* __restrict__ ob2,  // (32)
    const float* __restrict__ oW3,  // (32,32)
    const float* __restrict__ ob3,  // (32)
    const float* __restrict__ fW1,  // (64,32)
    const float* __restrict__ fb1,  // (64)
    const float* __restrict__ fW2,  // (1,64)
    const float* __restrict__ fb2,  // (1)
    float* __restrict__ outp)       // (B,1)
{
    const int tid  = threadIdx.x;
    const int lane = tid & 63;
    const int wid  = tid >> 6;
    const int b    = blockIdx.x * 4 + wid;
    const int r    = lane & 31;     // row within half-wave
    const int hf   = lane >> 5;     // half index

    // ---- LDS: GRU weights (col-major [col][32 rows]; lane r -> bank r) ----
    __shared__ float sWr[48 * 32];   // r-gate, cat = [x(16); h(32)]
    __shared__ float sWz[48 * 32];   // z-gate
    __shared__ float sWnh[32 * 32];  // n-gate, h part
    __shared__ float sWni[16 * 32];  // n-gate, x part
    __shared__ __align__(16) float buf[4][64];   // per-wave broadcast buffer

    for (int i = tid; i < 48 * 32; i += 256) {
        int c = i >> 5, r0 = i & 31;
        sWr[i] = (c < 16) ? gWih[r0 * 16 + c]        : gWhh[r0 * 32 + (c - 16)];
        sWz[i] = (c < 16) ? gWih[(32 + r0) * 16 + c] : gWhh[(32 + r0) * 32 + (c - 16)];
    }
    for (int i = tid; i < 32 * 32; i += 256) {
        int c = i >> 5, r0 = i & 31;
        sWnh[i] = gWhh[(64 + r0) * 32 + c];
    }
    for (int i = tid; i < 16 * 32; i += 256) {
        int c = i >> 5, r0 = i & 31;
        sWni[i] = gWih[(64 + r0) * 16 + c];
    }
    __syncthreads();

    float* bufw = buf[wid];
    const float4* bb = reinterpret_cast<const float4*>(bufw);

    // ------- ODE MLP weights -> NAMED per-lane f32x2 registers -------
    f32x2 w1_0, w1_1, w1_2, w1_3, w1_4, w1_5, w1_6, w1_7,
          w1_8, w1_9, w1_10, w1_11, w1_12, w1_13, w1_14, w1_15;
    f32x2 w2_0, w2_1, w2_2, w2_3, w2_4, w2_5, w2_6, w2_7,
          w2_8, w2_9, w2_10, w2_11, w2_12, w2_13, w2_14, w2_15;
    f32x2 w3_0, w3_1, w3_2, w3_3, w3_4, w3_5, w3_6, w3_7;
    {
        const float4* p1 = reinterpret_cast<const float4*>(oW1) + lane * 8;
        float4 v;
#define LD2(i, dA, dB) { v = p1[i]; dA = f32x2{v.x, v.y}; dB = f32x2{v.z, v.w}; }
        LD2(0, w1_0,  w1_1)  LD2(1, w1_2,  w1_3)
        LD2(2, w1_4,  w1_5)  LD2(3, w1_6,  w1_7)
        LD2(4, w1_8,  w1_9)  LD2(5, w1_10, w1_11)
        LD2(6, w1_12, w1_13) LD2(7, w1_14, w1_15)
#undef LD2
        const float4* p2 = reinterpret_cast<const float4*>(oW2) + r * 16 + hf * 8;
#define LD2(i, dA, dB) { v = p2[i]; dA = f32x2{v.x, v.y}; dB = f32x2{v.z, v.w}; }
        LD2(0, w2_0,  w2_1)  LD2(1, w2_2,  w2_3)
        LD2(2, w2_4,  w2_5)  LD2(3, w2_6,  w2_7)
        LD2(4, w2_8,  w2_9)  LD2(5, w2_10, w2_11)
        LD2(6, w2_12, w2_13) LD2(7, w2_14, w2_15)
#undef LD2
        const float4* p3 = reinterpret_cast<const float4*>(oW3) + r * 8 + hf * 4;
#define LD2(i, dA, dB) { v = p3[i]; dA = f32x2{v.x, v.y}; dB = f32x2{v.z, v.w}; }
        LD2(0, w3_0, w3_1)  LD2(1, w3_2, w3_3)
        LD2(2, w3_4, w3_5)  LD2(3, w3_6, w3_7)
#undef LD2
    }
    const float b1r = ob1[lane];
    const float b2r = ob2[r];
    const float b3r = ob3[r];

    const float brr = gbih[r]      + gbhh[r];
    const float bzz = gbih[32 + r] + gbhh[32 + r];
    const float bin = gbih[64 + r];
    const float bhn = gbhh[64 + r];

    // GRU weight LDS base pointers (per-lane, static offsets off these)
    const float* wrp  = &sWr[(hf * 24) * 32 + r];
    const float* wzp  = &sWz[(hf * 24) * 32 + r];
    const float* wnhp = &sWnh[(hf * 16) * 32 + r];
    const float* wnip = &sWni[r];

    // ------- ODE MLP: y (per-lane y[r], dup halves) -> k (same layout) -----
    // Math order identical to R6/R9 (absmax 0.0).
    auto ode_f = [&](float yv) -> float {
        bufw[hf * 32 + r] = yv;     // both halves write y[r]; reads use [0..31]
        fence();
        f32x2 acc1 = f32x2{b1r, 0.0f};
#define S1(kk, wA, wB) { float4 c = bb[kk]; \
        acc1 = pkfma(wA, f32x2{c.x, c.y}, acc1); \
        acc1 = pkfma(wB, f32x2{c.z, c.w}, acc1); }
        S1(0, w1_0,  w1_1)  S1(1, w1_2,  w1_3)
        S1(2, w1_4,  w1_5)  S1(3, w1_6,  w1_7)
        S1(4, w1_8,  w1_9)  S1(5, w1_10, w1_11)
        S1(6, w1_12, w1_13) S1(7, w1_14, w1_15)
#undef S1
        float a1 = fmaxf(acc1.x + acc1.y, 0.0f);
        bufw[lane] = a1;                           // h1 distributed over 64 lanes
        fence();
        f32x2 acc2 = f32x2{0.0f, 0.0f};
        const int o2 = hf * 8;
#define S2(kk, wA, wB) { float4 c = bb[o2 + kk]; \
        acc2 = pkfma(wA, f32x2{c.x, c.y}, acc2); \
        acc2 = pkfma(wB, f32x2{c.z, c.w}, acc2); }
        S2(0, w2_0,  w2_1)  S2(1, w2_2,  w2_3)
        S2(2, w2_4,  w2_5)  S2(3, w2_6,  w2_7)
        S2(4, w2_8,  w2_9)  S2(5, w2_10, w2_11)
        S2(6, w2_12, w2_13) S2(7, w2_14, w2_15)
#undef S2
        float a2 = fmaxf(xhsum(acc2.x + acc2.y) + b2r, 0.0f);
        bufw[hf * 32 + r] = a2;
        fence();
        f32x2 acc3 = f32x2{0.0f, 0.0f};
        const int o3 = hf * 4;
#define S3(kk, wA, wB) { float4 c = bb[o3 + kk]; \
        acc3 = pkfma(wA, f32x2{c.x, c.y}, acc3); \
        acc3 = pkfma(wB, f32x2{c.z, c.w}, acc3); }
        S3(0, w3_0, w3_1)  S3(1, w3_2, w3_3)
        S3(2, w3_4, w3_5)  S3(3, w3_6, w3_7)
#undef S3
        return xhsum(acc3.x + acc3.y) + b3r;
    };

    // ---------- time loop ----------
    float hv = 0.0f;      // hidden carry h[r] (dup halves)
    float outv = 0.0f;    // GRU output out[r] (dup halves)

    #pragma unroll 1
    for (int s = 0; s < NS - 1; ++s) {
        // stage cat = [x_t(16); h(32)] into bufw[0..47]
        const float* xrow = x + ((size_t)b * NS + s) * NI;
        if (hf == 0) {
            bufw[16 + r] = hv;
        } else {
            bufw[r & 15] = xrow[r & 15];   // duplicated writers, same data
        }
        fence();

        // r/z gates: 24 MACs per half each, weights from LDS (bank = r)
        float ar = 0.0f, az = 0.0f;
        #pragma unroll
        for (int kk = 0; kk < 6; ++kk) {
            float4 c = bb[hf*6 + kk];
            ar = fmaf(wrp[(4*kk  )*32], c.x, ar); ar = fmaf(wrp[(4*kk+1)*32], c.y, ar);
            ar = fmaf(wrp[(4*kk+2)*32], c.z, ar); ar = fmaf(wrp[(4*kk+3)*32], c.w, ar);
            az = fmaf(wzp[(4*kk  )*32], c.x, az); az = fmaf(wzp[(4*kk+1)*32], c.y, az);
            az = fmaf(wzp[(4*kk+2)*32], c.z, az); az = fmaf(wzp[(4*kk+3)*32], c.w, az);
        }
        // i_n: x-part (16 cols) — both halves compute FULL sum (dup).
        // h_n: 32 cols, k-split + cross-half sum.
        float in_ = 0.0f, hn = 0.0f;
        #pragma unroll
        for (int kk = 0; kk < 4; ++kk) {
            float4 c = bb[kk];
            in_ = fmaf(wnip[(4*kk  )*32], c.x, in_); in_ = fmaf(wnip[(4*kk+1)*32], c.y, in_);
            in_ = fmaf(wnip[(4*kk+2)*32], c.z, in_); in_ = fmaf(wnip[(4*kk+3)*32], c.w, in_);
        }
        #pragma unroll
        for (int kk = 0; kk < 4; ++kk) {
            float4 c = bb[4 + hf*4 + kk];
            hn = fmaf(wnhp[(4*kk  )*32], c.x, hn); hn = fmaf(wnhp[(4*kk+1)*32], c.y, hn);
            hn = fmaf(wnhp[(4*kk+2)*32], c.z, hn); hn = fmaf(wnhp[(4*kk+3)*32], c.w, hn);
        }
        ar = xhsum(ar) + brr;
        az = xhsum(az) + bzz;
        hn = xhsum(hn) + bhn;
        in_ += bin;

        float rg = 1.0f / (1.0f + __expf(-ar));
        float zg = 1.0f / (1.0f + __expf(-az));
        float ng = tanhf(fmaf(rg, hn, in_));
        outv = (1.0f - zg) * ng + zg * hv;

        hv = outv;
        if (s < NS - 2) {   // final step's ODE integration is dead -> skip
            const float t0 = t[(size_t)b * NS + s];
            const float t1 = t[(size_t)b * NS + s + 1];
            const float ddt = (t1 - t0) * 0.25f;   // dt / n_sub, n_sub = 4
            float hi = outv;
            #pragma unroll 1
            for (int sub = 0; sub < 4; ++sub) {
                float k1 = ode_f(hi);
                float k2 = ode_f(fmaf(ddt, 0.2f * k1, hi));
                float k3 = ode_f(fmaf(ddt, fmaf((float)(9.0/40.0), k2, (float)(3.0/40.0) * k1), hi));
                float k4 = ode_f(fmaf(ddt,
                        fmaf((float)(32.0/9.0), k3,
                        fmaf(-(float)(56.0/15.0), k2, (float)(44.0/45.0) * k1)), hi));
                float k5 = ode_f(fmaf(ddt,
                        fmaf(-(float)(212.0/729.0), k4,
                        fmaf((float)(64448.0/6561.0), k3,
                        fmaf(-(float)(25360.0/2187.0), k2, (float)(19372.0/6561.0) * k1))), hi));
                float k6 = ode_f(fmaf(ddt,
                        fmaf(-(float)(5103.0/18656.0), k5,
                        fmaf((float)(49.0/176.0), k4,
                        fmaf((float)(46732.0/5247.0), k3,
                        fmaf(-(float)(355.0/33.0), k2, (float)(9017.0/3168.0) * k1)))), hi));
                hi = fmaf(ddt,
                        fmaf((float)(11.0/84.0), k6,
                        fmaf(-(float)(2187.0/6784.0), k5,
                        fmaf((float)(125.0/192.0), k4,
                        fmaf((float)(500.0/1113.0), k3, (float)(35.0/384.0) * k1)))), hi);
            }
            hv = hi;
        }
    }

    // ---------- FC head: relu(out @ fW1.T + fb1) @ fW2.T + fb2 ----------
    bufw[hf * 32 + r] = outv;
    fence();
    f32x2 acc = f32x2{fb1[lane], 0.0f};
    {
        const float4* fw = reinterpret_cast<const float4*>(fW1) + lane * 8;
        #pragma unroll
        for (int kk = 0; kk < 8; ++kk) {
            float4 wv = fw[kk];
            float4 c  = bb[kk];
            acc = pkfma(f32x2{wv.x, wv.y}, f32x2{c.x, c.y}, acc);
            acc = pkfma(f32x2{wv.z, wv.w}, f32x2{c.z, c.w}, acc);
        }
    }
    float a = fmaxf(acc.x + acc.y, 0.0f);
    float p = a * fW2[lane];
    #pragma unroll
    for (int m = 1; m < 64; m <<= 1) p += __shfl_xor(p, m, 64);
    if (lane == 0) outp[b] = p + fb2[0];
}

extern "C" void kernel_launch(void* const* d_in, const int* in_sizes, int n_in,
                              void* d_out, int out_size, void* d_ws, size_t ws_size,
                              hipStream_t stream) {
    (void)in_sizes; (void)n_in; (void)d_ws; (void)ws_size; (void)out_size;
    odernn_kernel<<<dim3(NB / 4), dim3(256), 0, stream>>>(
        (const float*)d_in[0],  (const float*)d_in[1],
        (const float*)d_in[2],  (const float*)d_in[3],
        (const float*)d_in[4],  (const float*)d_in[5],
        (const float*)d_in[6],  (const float*)d_in[7],
        (const float*)d_in[8],  (const float*)d_in[9],
        (const float*)d_in[10], (const float*)d_in[11],
        (const float*)d_in[12], (const float*)d_in[13],
        (const float*)d_in[14], (const float*)d_in[15],
        (float*)d_out);
}